// Round 2
// baseline (122.428 us; speedup 1.0000x reference)
//
#include <hip/hip_runtime.h>
#include <math.h>

// KCanyon_Combined_Field: analytic gradient of the canyon potential.
//
//   dpot/dx = A*x - B*y ;  dpot/dy = A*y + B*x ;  output = -grad
//   A = a + (1-w)*b*dphi^2
//   B = (1-w)*b*dphi - 0.5*b*dphi^2 * dw_dphi
// with f = frac(phi * K/(2*pi)):
//   dphi = wrap(f)*(2*pi/K);  min_diff_m = |f-0.5|*(2*pi/K)
//   smooth region 1/8 < |f-0.5| < 1/4 (inner=pi/4K, outer=pi/2K)
//
// atan2 replaced by octant-reduced degree-11 minimax poly (max err ~2.3e-5 rad;
// worst-case output sensitivity ~5e3 -> <=0.12 added absmax vs 1.88 threshold).
//
// This revision: memory-path tuning only (math identical).
//  - 2x-unrolled grid-stride: two independent 16B loads in flight per thread
//    (32B/thread) to raise MLP toward the float4-copy BW ceiling (6.29 TB/s).
//  - nontemporal load/store hints: the 67MB input is read once and the 67MB
//    output is never re-read; avoid L2/LLC write-allocate pollution.

#define PI_F   3.14159265358979323846f
#define PI2_F  1.57079632679489661923f

typedef float f32x4 __attribute__((ext_vector_type(4)));
typedef float f32x2 __attribute__((ext_vector_type(2)));

__device__ __forceinline__ float fast_atan2f(float y, float x) {
    float ax = fabsf(x), ay = fabsf(y);
    float mx = fmaxf(ax, ay);
    float mn = fminf(ax, ay);
    float t = mn * __builtin_amdgcn_rcpf(mx);   // [0,1]; origin -> NaN (overwritten)
    float s = t * t;
    float p = fmaf(s, -0.01172120f, 0.05265332f);
    p = fmaf(s, p, -0.11643287f);
    p = fmaf(s, p,  0.19354346f);
    p = fmaf(s, p, -0.33262347f);
    p = fmaf(s, p,  0.99997726f);
    p = p * t;                                   // atan(mn/mx)
    p = (ay > ax) ? (PI2_F - p) : p;
    p = (x < 0.0f) ? (PI_F - p) : p;
    return copysignf(p, y);
}

__device__ __forceinline__ void grad_point(float x, float y, float a, float b,
                                           float c, float inv_c,
                                           float& ox, float& oy) {
    float phi = fast_atan2f(y, x);       // any branch: f is mod-1 invariant
    float t = phi * inv_c;               // inv_c = K/(2*pi)
    float f = t - floorf(t);             // [0,1)
    float u = (f > 0.5f) ? (f - 1.0f) : f;   // (-0.5, 0.5]
    float dphi = u * c;                  // c = 2*pi/K
    float fm = f - 0.5f;

    // branchless smooth-step: xs clamped to [0,1]; dss==0 exactly at the clamps
    float xs = fminf(fmaxf(8.0f * fabsf(fm) - 1.0f, 0.0f), 1.0f);
    float one_w = xs * xs * (3.0f - 2.0f * xs);          // = 1 - w
    float dss = 6.0f * xs * (1.0f - xs) * (8.0f * inv_c); // |dw/dphi|
    float dw_dphi = (fm >= 0.0f) ? -dss : dss;

    float bd = b * dphi;
    float A = a + one_w * bd * dphi;
    float B = one_w * bd - 0.5f * bd * dphi * dw_dphi;

    ox = -(A * x - B * y);
    oy = -(A * y + B * x);
    if (x == 0.0f && y == 0.0f) { ox = 0.0f; oy = 0.0f; }
}

__device__ __forceinline__ f32x4 grad_quad(f32x4 v, float a, float b,
                                           float c, float inv_c) {
    float o0, o1, o2, o3;
    grad_point(v.x, v.y, a, b, c, inv_c, o0, o1);
    grad_point(v.z, v.w, a, b, c, inv_c, o2, o3);
    f32x4 o;
    o.x = o0; o.y = o1; o.z = o2; o.w = o3;
    return o;
}

__global__ __launch_bounds__(256) void KCanyon_grad_kernel(
    const f32x4* __restrict__ xy4, const float* __restrict__ a_p,
    const float* __restrict__ b_p, f32x4* __restrict__ out4,
    int n4, int n_points, const f32x2* __restrict__ xy2,
    f32x2* __restrict__ out2, float c, float inv_c) {
    float a = fminf(fmaxf(a_p[0], 0.0f), 20.0f);
    float b = fminf(fmaxf(b_p[0], 0.0f), 20.0f);

    int stride = gridDim.x * blockDim.x;
    int i = blockIdx.x * blockDim.x + threadIdx.x;

    // Pairwise grid-stride: two independent 16B loads issued back-to-back,
    // compute both, then two 16B stores. Coalesced (lane-contiguous at both
    // i and i+stride), 32B of reads in flight per thread.
    for (; i + stride < n4; i += 2 * stride) {
        f32x4 v0 = __builtin_nontemporal_load(&xy4[i]);
        f32x4 v1 = __builtin_nontemporal_load(&xy4[i + stride]);
        f32x4 o0 = grad_quad(v0, a, b, c, inv_c);
        f32x4 o1 = grad_quad(v1, a, b, c, inv_c);
        __builtin_nontemporal_store(o0, &out4[i]);
        __builtin_nontemporal_store(o1, &out4[i + stride]);
    }
    if (i < n4) {   // at most one leftover index per thread
        f32x4 v = __builtin_nontemporal_load(&xy4[i]);
        f32x4 o = grad_quad(v, a, b, c, inv_c);
        __builtin_nontemporal_store(o, &out4[i]);
    }

    if (blockIdx.x == 0 && threadIdx.x == 0 && (n_points & 1)) {
        int last = n_points - 1;
        f32x2 v = xy2[last];
        float gx, gy;
        grad_point(v.x, v.y, a, b, c, inv_c, gx, gy);
        f32x2 o;
        o.x = gx; o.y = gy;
        out2[last] = o;
    }
}

extern "C" void kernel_launch(void* const* d_in, const int* in_sizes, int n_in,
                              void* d_out, int out_size, void* d_ws, size_t ws_size,
                              hipStream_t stream) {
    const float* xy  = (const float*)d_in[0];
    const float* a_p = (const float*)d_in[2];
    const float* b_p = (const float*)d_in[3];
    float* out = (float*)d_out;

    int K = in_sizes[1];                 // thetas are 2*pi*k/K by construction
    int n_points = out_size / 2;
    int n4 = out_size / 4;

    double cd = 6.283185307179586476925286766559 / (double)K;
    float c = (float)cd;
    float inv_c = (float)(1.0 / cd);

    int block = 256;
    int grid = (n4 + block * 2 - 1) / (block * 2);   // each thread covers 2 float4s
    if (grid < 1) grid = 1;
    KCanyon_grad_kernel<<<grid, block, 0, stream>>>(
        (const f32x4*)xy, a_p, b_p, (f32x4*)out, n4, n_points,
        (const f32x2*)xy, (f32x2*)out, c, inv_c);
}

// Round 3
// 117.066 us; speedup vs baseline: 1.0458x; 1.0458x over previous
//
#include <hip/hip_runtime.h>
#include <math.h>

// KCanyon_Combined_Field: analytic gradient of the canyon potential.
//
//   dpot/dx = A*x - B*y ;  dpot/dy = A*y + B*x ;  output = -grad
//   A = a + (1-w)*b*dphi^2
//   B = (1-w)*b*dphi - 0.5*b*dphi^2 * dw_dphi
// with f = frac(phi * K/(2*pi)):
//   dphi = wrap(f)*(2*pi/K);  min_diff_m = |f-0.5|*(2*pi/K)
//   smooth region 1/8 < |f-0.5| < 1/4 (inner=pi/4K, outer=pi/2K)
//
// atan2 replaced by octant-reduced degree-11 minimax poly (max err ~2.3e-5 rad;
// worst-case output sensitivity ~5e3 -> <=0.12 added absmax vs 1.88 threshold).
//
// R2 post-mortem: nontemporal hints REGRESSED (114.6 -> 122.4 us). The 67MB
// input is LLC-resident across bench iterations; nt loads (evict-first)
// forced HBM re-fetch (~+10.6 us/iter, matching the observed delta).
// This revision: plain cached loads/stores (LLC-friendly), keep ONLY the
// 2x-unrolled grid-stride (two independent 16B loads in flight per thread).

#define PI_F   3.14159265358979323846f
#define PI2_F  1.57079632679489661923f

__device__ __forceinline__ float fast_atan2f(float y, float x) {
    float ax = fabsf(x), ay = fabsf(y);
    float mx = fmaxf(ax, ay);
    float mn = fminf(ax, ay);
    float t = mn * __builtin_amdgcn_rcpf(mx);   // [0,1]; origin -> NaN (overwritten)
    float s = t * t;
    float p = fmaf(s, -0.01172120f, 0.05265332f);
    p = fmaf(s, p, -0.11643287f);
    p = fmaf(s, p,  0.19354346f);
    p = fmaf(s, p, -0.33262347f);
    p = fmaf(s, p,  0.99997726f);
    p = p * t;                                   // atan(mn/mx)
    p = (ay > ax) ? (PI2_F - p) : p;
    p = (x < 0.0f) ? (PI_F - p) : p;
    return copysignf(p, y);
}

__device__ __forceinline__ void grad_point(float x, float y, float a, float b,
                                           float c, float inv_c,
                                           float& ox, float& oy) {
    float phi = fast_atan2f(y, x);       // any branch: f is mod-1 invariant
    float t = phi * inv_c;               // inv_c = K/(2*pi)
    float f = t - floorf(t);             // [0,1)
    float u = (f > 0.5f) ? (f - 1.0f) : f;   // (-0.5, 0.5]
    float dphi = u * c;                  // c = 2*pi/K
    float fm = f - 0.5f;

    // branchless smooth-step: xs clamped to [0,1]; dss==0 exactly at the clamps
    float xs = fminf(fmaxf(8.0f * fabsf(fm) - 1.0f, 0.0f), 1.0f);
    float one_w = xs * xs * (3.0f - 2.0f * xs);          // = 1 - w
    float dss = 6.0f * xs * (1.0f - xs) * (8.0f * inv_c); // |dw/dphi|
    float dw_dphi = (fm >= 0.0f) ? -dss : dss;

    float bd = b * dphi;
    float A = a + one_w * bd * dphi;
    float B = one_w * bd - 0.5f * bd * dphi * dw_dphi;

    ox = -(A * x - B * y);
    oy = -(A * y + B * x);
    if (x == 0.0f && y == 0.0f) { ox = 0.0f; oy = 0.0f; }
}

__global__ __launch_bounds__(256) void KCanyon_grad_kernel(
    const float4* __restrict__ xy4, const float* __restrict__ a_p,
    const float* __restrict__ b_p, float4* __restrict__ out4,
    int n4, int n_points, const float2* __restrict__ xy2,
    float2* __restrict__ out2, float c, float inv_c) {
    float a = fminf(fmaxf(a_p[0], 0.0f), 20.0f);
    float b = fminf(fmaxf(b_p[0], 0.0f), 20.0f);

    int stride = gridDim.x * blockDim.x;
    int i = blockIdx.x * blockDim.x + threadIdx.x;

    // Pairwise grid-stride: two independent 16B loads issued back-to-back,
    // compute both, then two 16B stores. Coalesced (lane-contiguous at both
    // i and i+stride), 32B of reads in flight per thread.
    for (; i + stride < n4; i += 2 * stride) {
        float4 v0 = xy4[i];
        float4 v1 = xy4[i + stride];
        float4 o0, o1;
        grad_point(v0.x, v0.y, a, b, c, inv_c, o0.x, o0.y);
        grad_point(v0.z, v0.w, a, b, c, inv_c, o0.z, o0.w);
        grad_point(v1.x, v1.y, a, b, c, inv_c, o1.x, o1.y);
        grad_point(v1.z, v1.w, a, b, c, inv_c, o1.z, o1.w);
        out4[i] = o0;
        out4[i + stride] = o1;
    }
    if (i < n4) {   // at most one leftover index per thread
        float4 v = xy4[i];
        float4 o;
        grad_point(v.x, v.y, a, b, c, inv_c, o.x, o.y);
        grad_point(v.z, v.w, a, b, c, inv_c, o.z, o.w);
        out4[i] = o;
    }

    if (blockIdx.x == 0 && threadIdx.x == 0 && (n_points & 1)) {
        int last = n_points - 1;
        float2 v = xy2[last];
        float2 o;
        grad_point(v.x, v.y, a, b, c, inv_c, o.x, o.y);
        out2[last] = o;
    }
}

extern "C" void kernel_launch(void* const* d_in, const int* in_sizes, int n_in,
                              void* d_out, int out_size, void* d_ws, size_t ws_size,
                              hipStream_t stream) {
    const float* xy  = (const float*)d_in[0];
    const float* a_p = (const float*)d_in[2];
    const float* b_p = (const float*)d_in[3];
    float* out = (float*)d_out;

    int K = in_sizes[1];                 // thetas are 2*pi*k/K by construction
    int n_points = out_size / 2;
    int n4 = out_size / 4;

    double cd = 6.283185307179586476925286766559 / (double)K;
    float c = (float)cd;
    float inv_c = (float)(1.0 / cd);

    int block = 256;
    int grid = (n4 + block * 2 - 1) / (block * 2);   // each thread covers 2 float4s
    if (grid < 1) grid = 1;
    KCanyon_grad_kernel<<<grid, block, 0, stream>>>(
        (const float4*)xy, a_p, b_p, (float4*)out, n4, n_points,
        (const float2*)xy, (float2*)out, c, inv_c);
}

// Round 4
// 114.981 us; speedup vs baseline: 1.0648x; 1.0181x over previous
//
#include <hip/hip_runtime.h>
#include <math.h>

// KCanyon_Combined_Field: analytic gradient of the canyon potential.
//
//   dpot/dx = A*x - B*y ;  dpot/dy = A*y + B*x ;  output = -grad
//   A = a + (1-w)*b*dphi^2
//   B = (1-w)*b*dphi - 0.5*b*dphi^2 * dw_dphi
// with f = frac(phi * K/(2*pi)):
//   dphi = wrap(f)*(2*pi/K);  min_diff_m = |f-0.5|*(2*pi/K)
//   smooth region 1/8 < |f-0.5| < 1/4 (inner=pi/4K, outer=pi/2K)
//
// atan2 replaced by octant-reduced degree-11 minimax poly (max err ~2.3e-5 rad;
// worst-case output sensitivity ~5e3 -> <=0.12 added absmax vs 1.88 threshold).
//
// Session history:
//  R0 baseline (this structure): 114.6 us.
//  R2 nt-hints + 2x-unroll: 122.4 us (nt evicts LLC-resident input: ~-5.3 us;
//     unroll splits streams 32MB apart, hurts DRAM locality: ~-2.5 us).
//  R3 unroll-only: 117.1 us (confirms both attributions).
// This revision: exact R0 memory structure (1 float4/thread, plain loads)
// + K==8 fast path: sector width == octant width, so f = mirror ? 1-s : s
// with s = atan(mn/mx)*(4/pi) (4/pi folded into poly coeffs) and
// mirror = (ay>ax) ^ (x<0) ^ (y<0). Deletes phi-reconstruction selects,
// copysign, *inv_c, floorf from the load->store dependent chain (~6 ops).
// Verified vs reference mapping at phi=30/60/100/170/190/350 deg + axes;
// f==1 occurs only where u==0 and dss==0, so outputs are unchanged.

#define PI_F   3.14159265358979323846f
#define PI2_F  1.57079632679489661923f

__device__ __forceinline__ float fast_atan2f(float y, float x) {
    float ax = fabsf(x), ay = fabsf(y);
    float mx = fmaxf(ax, ay);
    float mn = fminf(ax, ay);
    float t = mn * __builtin_amdgcn_rcpf(mx);   // [0,1]; origin -> NaN (overwritten)
    float s = t * t;
    float p = fmaf(s, -0.01172120f, 0.05265332f);
    p = fmaf(s, p, -0.11643287f);
    p = fmaf(s, p,  0.19354346f);
    p = fmaf(s, p, -0.33262347f);
    p = fmaf(s, p,  0.99997726f);
    p = p * t;                                   // atan(mn/mx)
    p = (ay > ax) ? (PI2_F - p) : p;
    p = (x < 0.0f) ? (PI_F - p) : p;
    return copysignf(p, y);
}

// Shared tail: from f in [0,1] (f==1 allowed only where u==0, dss==0)
__device__ __forceinline__ void grad_tail(float x, float y, float a, float b,
                                          float c, float inv_c, float f,
                                          float& ox, float& oy) {
    float u = (f > 0.5f) ? (f - 1.0f) : f;   // (-0.5, 0.5]
    float dphi = u * c;                  // c = 2*pi/K
    float fm = f - 0.5f;

    // branchless smooth-step: xs clamped to [0,1]; dss==0 exactly at the clamps
    float xs = fminf(fmaxf(8.0f * fabsf(fm) - 1.0f, 0.0f), 1.0f);
    float one_w = xs * xs * (3.0f - 2.0f * xs);          // = 1 - w
    float dss = 6.0f * xs * (1.0f - xs) * (8.0f * inv_c); // |dw/dphi|
    float dw_dphi = (fm >= 0.0f) ? -dss : dss;

    float bd = b * dphi;
    float A = a + one_w * bd * dphi;
    float B = one_w * bd - 0.5f * bd * dphi * dw_dphi;

    ox = -(A * x - B * y);
    oy = -(A * y + B * x);
    if (x == 0.0f && y == 0.0f) { ox = 0.0f; oy = 0.0f; }
}

template<bool K8>
__device__ __forceinline__ void grad_point(float x, float y, float a, float b,
                                           float c, float inv_c,
                                           float& ox, float& oy) {
    float f;
    if (K8) {
        // K==8: sector width (45 deg) == octant width of the atan2 reduction.
        // s = atan(mn/mx) * (4/pi) in "sector units"; coeffs = minimax * 4/pi.
        float ax = fabsf(x), ay = fabsf(y);
        float mx = fmaxf(ax, ay);
        float mn = fminf(ax, ay);
        float t = mn * __builtin_amdgcn_rcpf(mx);   // [0,1]; origin -> NaN
        float q = t * t;
        float p = fmaf(q, -0.01492388f, 0.06704029f);
        p = fmaf(q, p, -0.14824687f);
        p = fmaf(q, p,  0.24642721f);
        p = fmaf(q, p, -0.42350939f);
        p = fmaf(q, p,  1.27321059f);
        float s = p * t;                             // in [0,1]
        bool mirror = (ay > ax) != (x < 0.0f);
        mirror = mirror != (y < 0.0f);
        f = mirror ? (1.0f - s) : s;
    } else {
        float phi = fast_atan2f(y, x);   // any branch: f is mod-1 invariant
        float t = phi * inv_c;           // inv_c = K/(2*pi)
        f = t - floorf(t);               // [0,1)
    }
    grad_tail(x, y, a, b, c, inv_c, f, ox, oy);
}

template<bool K8>
__global__ __launch_bounds__(256) void KCanyon_grad_kernel(
    const float4* __restrict__ xy4, const float* __restrict__ a_p,
    const float* __restrict__ b_p, float4* __restrict__ out4,
    int n4, int n_points, const float2* __restrict__ xy2,
    float2* __restrict__ out2, float c, float inv_c) {
    float a = fminf(fmaxf(a_p[0], 0.0f), 20.0f);
    float b = fminf(fmaxf(b_p[0], 0.0f), 20.0f);

    int i = blockIdx.x * blockDim.x + threadIdx.x;
    int stride = gridDim.x * blockDim.x;
    for (; i < n4; i += stride) {
        float4 v = xy4[i];
        float4 o;
        grad_point<K8>(v.x, v.y, a, b, c, inv_c, o.x, o.y);
        grad_point<K8>(v.z, v.w, a, b, c, inv_c, o.z, o.w);
        out4[i] = o;
    }
    if (blockIdx.x == 0 && threadIdx.x == 0 && (n_points & 1)) {
        int last = n_points - 1;
        float2 v = xy2[last];
        float2 o;
        grad_point<K8>(v.x, v.y, a, b, c, inv_c, o.x, o.y);
        out2[last] = o;
    }
}

extern "C" void kernel_launch(void* const* d_in, const int* in_sizes, int n_in,
                              void* d_out, int out_size, void* d_ws, size_t ws_size,
                              hipStream_t stream) {
    const float* xy  = (const float*)d_in[0];
    const float* a_p = (const float*)d_in[2];
    const float* b_p = (const float*)d_in[3];
    float* out = (float*)d_out;

    int K = in_sizes[1];                 // thetas are 2*pi*k/K by construction
    int n_points = out_size / 2;
    int n4 = out_size / 4;

    double cd = 6.283185307179586476925286766559 / (double)K;
    float c = (float)cd;
    float inv_c = (float)(1.0 / cd);

    int block = 256;
    int grid = (n4 + block - 1) / block;
    if (grid < 1) grid = 1;
    if (K == 8) {
        KCanyon_grad_kernel<true><<<grid, block, 0, stream>>>(
            (const float4*)xy, a_p, b_p, (float4*)out, n4, n_points,
            (const float2*)xy, (float2*)out, c, inv_c);
    } else {
        KCanyon_grad_kernel<false><<<grid, block, 0, stream>>>(
            (const float4*)xy, a_p, b_p, (float4*)out, n4, n_points,
            (const float2*)xy, (float2*)out, c, inv_c);
    }
}